// Round 4
// baseline (1280.941 us; speedup 1.0000x reference)
//
#include <hip/hip_runtime.h>
#include <hip/hip_bf16.h>
#include <math.h>

#define BB 32
#define SS 32
#define DD 768
#define FFD 3072
#define EE 8
#define KK 2
#define NPAIR 64
#define MAXT 22   // max expert-aligned tiles of 4 pairs

typedef __attribute__((ext_vector_type(8))) short short8;
typedef __attribute__((ext_vector_type(4))) float f32x4;
typedef __attribute__((ext_vector_type(8))) unsigned short us8;

// ws int layout: [0..63] gates, [64..127] spair (pairs grouped by expert),
//   [128..149] te_expert, [152..173] te_slot0, [176..197] te_np
// H (bf16 [64*32][3072]) at ws byte offset 1024.

__device__ __forceinline__ unsigned short f2bf(float f) {
    __hip_bfloat16 h = __float2bfloat16(f);
    return __builtin_bit_cast(unsigned short, h);
}

// swizzled LDS byte offset: 128B rows, XOR bits 4-6 with row&7
__device__ __forceinline__ int lds_off(int row, int byte_in_row) {
    return row * 128 + (byte_in_row ^ ((row & 7) << 4));
}

// ---------------------------------------------------------------------------
__global__ __launch_bounds__(256) void gate_kernel(
    const float* __restrict__ x, const float* __restrict__ Wg,
    const float* __restrict__ bg, float* __restrict__ out,
    int* __restrict__ gates)
{
    int b = blockIdx.x;
    int tid = threadIdx.x;

    float acc[EE];
#pragma unroll
    for (int e = 0; e < EE; ++e) acc[e] = 0.f;

    for (int d = tid; d < DD; d += 256) {
        float xs = 0.f;
        const float* xp = x + (size_t)b * SS * DD + d;
#pragma unroll
        for (int s = 0; s < SS; ++s) xs += xp[(size_t)s * DD];
#pragma unroll
        for (int e = 0; e < EE; ++e) acc[e] += xs * Wg[d * EE + e];
    }

    __shared__ float red[EE][256];
#pragma unroll
    for (int e = 0; e < EE; ++e) red[e][tid] = acc[e];
    __syncthreads();
    for (int off = 128; off > 0; off >>= 1) {
        if (tid < off) {
#pragma unroll
            for (int e = 0; e < EE; ++e) red[e][tid] += red[e][tid + off];
        }
        __syncthreads();
    }

    if (tid == 0) {
        float lg[EE], p[EE];
        float m = -1e30f;
#pragma unroll
        for (int e = 0; e < EE; ++e) {
            lg[e] = red[e][0] / (float)SS + bg[e];
            m = fmaxf(m, lg[e]);
        }
        float sum = 0.f;
#pragma unroll
        for (int e = 0; e < EE; ++e) { p[e] = expf(lg[e] - m); sum += p[e]; }
        float inv = 1.f / sum;
#pragma unroll
        for (int e = 0; e < EE; ++e) p[e] *= inv;

        int i1 = 0;
        for (int e = 1; e < EE; ++e) if (p[e] > p[i1]) i1 = e;
        int i2 = (i1 == 0) ? 1 : 0;
        for (int e = 0; e < EE; ++e) if (e != i1 && p[e] > p[i2]) i2 = e;

        float* prob_out = out + (size_t)BB * SS * DD;
        float* gate_out = prob_out + BB * KK;
        prob_out[b * KK + 0] = p[i1];
        prob_out[b * KK + 1] = p[i2];
        gate_out[b * KK + 0] = (float)i1;
        gate_out[b * KK + 1] = (float)i2;
        gates[b * KK + 0] = i1;
        gates[b * KK + 1] = i2;
    }
}

// ---------------------------------------------------------------------------
// schedule: group pairs by expert, tiles of 4 pairs (BM=128 rows)
__global__ void sched_kernel(int* __restrict__ wsi)
{
    if (threadIdx.x != 0 || blockIdx.x != 0) return;
    const int* gates = wsi;
    int* spair = wsi + 64;
    int* te_e = wsi + 128;
    int* te_s = wsi + 152;
    int* te_n = wsi + 176;

    int cnt[EE];
    for (int e = 0; e < EE; ++e) cnt[e] = 0;
    for (int p = 0; p < NPAIR; ++p) cnt[gates[p]]++;
    int start[EE + 1];
    start[0] = 0;
    for (int e = 0; e < EE; ++e) start[e + 1] = start[e] + cnt[e];
    int fill[EE];
    for (int e = 0; e < EE; ++e) fill[e] = start[e];
    for (int p = 0; p < NPAIR; ++p) spair[fill[gates[p]]++] = p;

    int t = 0;
    for (int e = 0; e < EE; ++e) {
        for (int o = 0; o < cnt[e]; o += 4) {
            te_e[t] = e;
            te_s[t] = start[e] + o;
            te_n[t] = (cnt[e] - o) < 4 ? (cnt[e] - o) : 4;
            ++t;
        }
    }
    for (; t < MAXT; ++t) te_n[t] = 0;
}

// ---------------------------------------------------------------------------
__global__ __launch_bounds__(256) void init_kernel(
    const int* __restrict__ gates, const float* __restrict__ b2,
    float* __restrict__ out)
{
    int idx = blockIdx.x * 256 + threadIdx.x;
    if (idx >= BB * SS * DD) return;
    int b = idx / (SS * DD);
    int d = idx % DD;
    int e0 = gates[b * KK + 0];
    int e1 = gates[b * KK + 1];
    out[idx] = b2[e0 * DD + d] + b2[e1 * DD + d];
}

// ---------------------------------------------------------------------------
// Up GEMM: H = gelu(x @ W1[e] + b1[e]); BM=128 BN=64 BK=64, 4 waves 2x2
// (wave-tile 64x32), reg dbuf + LDS dbuf. grid (48 nt, MAXT). 48%8==0 so
// same-expert tiles (stride 48 in linear id) share an XCD -> W1 L2 reuse.
__global__ __launch_bounds__(256, 3) void up_gemm(
    const float* __restrict__ x, const float* __restrict__ W1,
    const float* __restrict__ b1, const int* __restrict__ wsi,
    unsigned short* __restrict__ H)
{
    int tile = blockIdx.y;
    int np = wsi[176 + tile];
    if (np == 0) return;
    int e = wsi[128 + tile];
    int slot0 = wsi[152 + tile];
    int nt = blockIdx.x;
    int tid = threadIdx.x;
    int wid = tid >> 6, lane = tid & 63;
    int wm = wid >> 1, wn = wid & 1;

    __shared__ char lds[49152];   // per buf: A 16KB + B 8KB

    // A staging setup (x fp32 gathered rows -> bf16); clamp tail rows
    const float* asrc[4];
    int aoff[4];
#pragma unroll
    for (int i = 0; i < 4; ++i) {
        int c = tid + i * 256;            // 0..1023
        int row = c >> 3, ch = c & 7;     // 128 rows x 8 chunks of 8 elems
        int lp = row >> 5;
        int lpc = lp < np ? lp : np - 1;
        int pair = wsi[64 + slot0 + lpc];
        int b = pair >> 1;
        asrc[i] = x + ((size_t)(b * SS + (row & 31))) * DD + ch * 8;
        aoff[i] = lds_off(row, ch * 16);
    }
    // B staging setup: [n][k] LDS; lanes sweep n (coalesced), k strided
    int n = tid & 63, kq = tid >> 6;
    const float* bsrc = W1 + ((size_t)e * DD + kq * 16) * FFD + nt * 64 + n;
    int boff[2];
#pragma unroll
    for (int j4 = 0; j4 < 2; ++j4) boff[j4] = lds_off(n, kq * 32 + j4 * 16);

    f32x4 acc[4][2];
#pragma unroll
    for (int i = 0; i < 4; ++i)
#pragma unroll
        for (int j = 0; j < 2; ++j) acc[i][j] = (f32x4)0.f;

    float bB0[16], bB1[16];
    float4 bA0[4][2], bA1[4][2];

    auto issue = [&](int k0, float (&bB)[16], float4 (&bA)[4][2]) {
        const float* wp = bsrc + (size_t)k0 * FFD;   // cold HBM stream first
#pragma unroll
        for (int j = 0; j < 16; ++j) bB[j] = wp[(size_t)j * FFD];
#pragma unroll
        for (int i = 0; i < 4; ++i) {
            bA[i][0] = *(const float4*)(asrc[i] + k0);
            bA[i][1] = *(const float4*)(asrc[i] + k0 + 4);
        }
    };
    auto store = [&](int p, const float (&bB)[16], const float4 (&bA)[4][2]) {
        char* Al = lds + p * 24576;
        char* Bl = Al + 16384;
#pragma unroll
        for (int i = 0; i < 4; ++i) {
            us8 u;
            u[0] = f2bf(bA[i][0].x); u[1] = f2bf(bA[i][0].y);
            u[2] = f2bf(bA[i][0].z); u[3] = f2bf(bA[i][0].w);
            u[4] = f2bf(bA[i][1].x); u[5] = f2bf(bA[i][1].y);
            u[6] = f2bf(bA[i][1].z); u[7] = f2bf(bA[i][1].w);
            *(us8*)(Al + aoff[i]) = u;
        }
#pragma unroll
        for (int j4 = 0; j4 < 2; ++j4) {
            us8 u;
#pragma unroll
            for (int m = 0; m < 8; ++m) u[m] = f2bf(bB[j4 * 8 + m]);
            *(us8*)(Bl + boff[j4]) = u;
        }
    };
    auto compute = [&](int p) {
        char* Al = lds + p * 24576;
        char* Bl = Al + 16384;
#pragma unroll
        for (int kk = 0; kk < 2; ++kk) {
            int kb = kk * 64 + (lane >> 4) * 16;
            short8 af[4], bf[2];
#pragma unroll
            for (int mf = 0; mf < 4; ++mf)
                af[mf] = *(short8*)(Al + lds_off(wm * 64 + mf * 16 + (lane & 15), kb));
#pragma unroll
            for (int nf = 0; nf < 2; ++nf)
                bf[nf] = *(short8*)(Bl + lds_off(wn * 32 + nf * 16 + (lane & 15), kb));
#pragma unroll
            for (int mf = 0; mf < 4; ++mf)
#pragma unroll
                for (int nf = 0; nf < 2; ++nf)
                    acc[mf][nf] = __builtin_amdgcn_mfma_f32_16x16x32_bf16(
                        af[mf], bf[nf], acc[mf][nf], 0, 0, 0);
        }
    };

    // 12 k-steps (DD/64). Two reg buffers -> loads issued ~1.5 steps ahead.
    issue(0, bB0, bA0);
    issue(64, bB1, bA1);
    store(0, bB0, bA0);
    __syncthreads();
    for (int s = 0; s < 12; s += 2) {
        compute(0);
        if (s < 10) issue((s + 2) * 64, bB0, bA0);
        store(1, bB1, bA1);
        __syncthreads();
        compute(1);
        if (s < 10) {
            issue((s + 3) * 64, bB1, bA1);
            store(0, bB0, bA0);
        }
        __syncthreads();
    }

    // epilogue: bias + exact gelu -> bf16 H (grouped slot rows)
    float bias[2];
#pragma unroll
    for (int nf = 0; nf < 2; ++nf)
        bias[nf] = b1[e * FFD + nt * 64 + wn * 32 + nf * 16 + (lane & 15)];
#pragma unroll
    for (int mf = 0; mf < 4; ++mf) {
#pragma unroll
        for (int i = 0; i < 4; ++i) {
            int row = wm * 64 + mf * 16 + (lane >> 4) * 4 + i;
            if ((row >> 5) >= np) continue;
            size_t srow = (size_t)(slot0 * 32 + row);
#pragma unroll
            for (int nf = 0; nf < 2; ++nf) {
                int f = nt * 64 + wn * 32 + nf * 16 + (lane & 15);
                float h = acc[mf][nf][i] + bias[nf];
                float g = 0.5f * h * (1.0f + erff(h * 0.70710678118654752f));
                H[srow * FFD + f] = f2bf(g);
            }
        }
    }
}

// ---------------------------------------------------------------------------
// Down GEMM: out += H @ W2[e]; BM=128 BN=64 BK=64, K split x4.
// grid (16 nt [12 real, padded so stride%8==0 for XCD-L2 reuse], MAXT, 4)
__global__ __launch_bounds__(256, 3) void down_gemm(
    const unsigned short* __restrict__ H, const float* __restrict__ W2,
    const int* __restrict__ wsi, float* __restrict__ out)
{
    int nt = blockIdx.x;
    if (nt >= DD / 64) return;
    int tile = blockIdx.y;
    int np = wsi[176 + tile];
    if (np == 0) return;
    int e = wsi[128 + tile];
    int slot0 = wsi[152 + tile];
    int zb = blockIdx.z * (FFD / 4);
    int tid = threadIdx.x;
    int wid = tid >> 6, lane = tid & 63;
    int wm = wid >> 1, wn = wid & 1;

    __shared__ char lds[49152];

    // A staging setup (H bf16, contiguous grouped rows; clamp tail rows)
    const unsigned short* asrc[4];
    int aoff[4];
#pragma unroll
    for (int i = 0; i < 4; ++i) {
        int c = tid + i * 256;
        int row = c >> 3, ch = c & 7;
        int rc = row < np * 32 ? row : np * 32 - 1;
        asrc[i] = H + (size_t)(slot0 * 32 + rc) * FFD + zb + ch * 8;
        aoff[i] = lds_off(row, ch * 16);
    }
    int n = tid & 63, kq = tid >> 6;
    const float* bsrc = W2 + ((size_t)e * FFD + zb + kq * 16) * DD + nt * 64 + n;
    int boff[2];
#pragma unroll
    for (int j4 = 0; j4 < 2; ++j4) boff[j4] = lds_off(n, kq * 32 + j4 * 16);

    f32x4 acc[4][2];
#pragma unroll
    for (int i = 0; i < 4; ++i)
#pragma unroll
        for (int j = 0; j < 2; ++j) acc[i][j] = (f32x4)0.f;

    float bB0[16], bB1[16];
    us8 bA0[4], bA1[4];

    auto issue = [&](int k0, float (&bB)[16], us8 (&bA)[4]) {
        const float* wp = bsrc + (size_t)k0 * DD;
#pragma unroll
        for (int j = 0; j < 16; ++j) bB[j] = wp[(size_t)j * DD];
#pragma unroll
        for (int i = 0; i < 4; ++i) bA[i] = *(const us8*)(asrc[i] + k0);
    };
    auto store = [&](int p, const float (&bB)[16], const us8 (&bA)[4]) {
        char* Al = lds + p * 24576;
        char* Bl = Al + 16384;
#pragma unroll
        for (int i = 0; i < 4; ++i) *(us8*)(Al + aoff[i]) = bA[i];
#pragma unroll
        for (int j4 = 0; j4 < 2; ++j4) {
            us8 u;
#pragma unroll
            for (int m = 0; m < 8; ++m) u[m] = f2bf(bB[j4 * 8 + m]);
            *(us8*)(Bl + boff[j4]) = u;
        }
    };
    auto compute = [&](int p) {
        char* Al = lds + p * 24576;
        char* Bl = Al + 16384;
#pragma unroll
        for (int kk = 0; kk < 2; ++kk) {
            int kb = kk * 64 + (lane >> 4) * 16;
            short8 af[4], bf[2];
#pragma unroll
            for (int mf = 0; mf < 4; ++mf)
                af[mf] = *(short8*)(Al + lds_off(wm * 64 + mf * 16 + (lane & 15), kb));
#pragma unroll
            for (int nf = 0; nf < 2; ++nf)
                bf[nf] = *(short8*)(Bl + lds_off(wn * 32 + nf * 16 + (lane & 15), kb));
#pragma unroll
            for (int mf = 0; mf < 4; ++mf)
#pragma unroll
                for (int nf = 0; nf < 2; ++nf)
                    acc[mf][nf] = __builtin_amdgcn_mfma_f32_16x16x32_bf16(
                        af[mf], bf[nf], acc[mf][nf], 0, 0, 0);
        }
    };

    issue(0, bB0, bA0);
    issue(64, bB1, bA1);
    store(0, bB0, bA0);
    __syncthreads();
    for (int s = 0; s < 12; s += 2) {
        compute(0);
        if (s < 10) issue((s + 2) * 64, bB0, bA0);
        store(1, bB1, bA1);
        __syncthreads();
        compute(1);
        if (s < 10) {
            issue((s + 3) * 64, bB1, bA1);
            store(0, bB0, bA0);
        }
        __syncthreads();
    }

    // epilogue: scatter atomic-add (bias pre-added by init_kernel)
#pragma unroll
    for (int mf = 0; mf < 4; ++mf) {
#pragma unroll
        for (int i = 0; i < 4; ++i) {
            int row = wm * 64 + mf * 16 + (lane >> 4) * 4 + i;
            int lp = row >> 5;
            if (lp >= np) continue;
            int pair = wsi[64 + slot0 + lp];
            int b = pair >> 1;
            int sI = row & 31;
            float* op = out + ((size_t)(b * SS + sI)) * DD + nt * 64 + wn * 32 + (lane & 15);
#pragma unroll
            for (int nf = 0; nf < 2; ++nf)
                atomicAdd(op + nf * 16, acc[mf][nf][i]);
        }
    }
}

// ---------------------------------------------------------------------------
extern "C" void kernel_launch(void* const* d_in, const int* in_sizes, int n_in,
                              void* d_out, int out_size, void* d_ws, size_t ws_size,
                              hipStream_t stream) {
    const float* x  = (const float*)d_in[0];
    const float* Wg = (const float*)d_in[2];
    const float* bg = (const float*)d_in[3];
    const float* W1 = (const float*)d_in[4];
    const float* b1 = (const float*)d_in[5];
    const float* W2 = (const float*)d_in[6];
    const float* b2 = (const float*)d_in[7];
    float* out = (float*)d_out;

    int* wsi = (int*)d_ws;
    unsigned short* H = (unsigned short*)((char*)d_ws + 1024);
    // ws needed: 1024 + 64*32*3072*2 = ~12.6 MB

    gate_kernel<<<BB, 256, 0, stream>>>(x, Wg, bg, out, wsi);
    sched_kernel<<<1, 64, 0, stream>>>(wsi);
    init_kernel<<<(BB * SS * DD + 255) / 256, 256, 0, stream>>>(wsi, b2, out);
    up_gemm<<<dim3(48, MAXT), 256, 0, stream>>>(x, W1, b1, wsi, H);
    down_gemm<<<dim3(16, MAXT, 4), 256, 0, stream>>>(H, W2, wsi, out);
}

// Round 5
// 119.057 us; speedup vs baseline: 10.7590x; 10.7590x over previous
//
#include <hip/hip_runtime.h>
#include <hip/hip_bf16.h>
#include <math.h>

#define BB 32
#define SS 32
#define DD 768
#define FFD 3072
#define EE 8
#define KK 2
#define NPAIR 64
#define MAXT 22   // max expert-aligned tiles of 4 pairs

#define GLOBAL_AS __attribute__((address_space(1)))
#define LDS_AS    __attribute__((address_space(3)))

typedef __attribute__((ext_vector_type(8))) short short8;
typedef __attribute__((ext_vector_type(4))) float f32x4;
typedef __attribute__((ext_vector_type(8))) unsigned short us8;

// ws int layout: [0..63] gates, [64..127] spair (pairs grouped by expert),
//   [128..149] te_expert, [152..173] te_slot0, [176..197] te_np
// H (bf16 [64*32][3072]) at ws byte offset 1024.

__device__ __forceinline__ unsigned short f2bf(float f) {
    __hip_bfloat16 h = __float2bfloat16(f);
    return __builtin_bit_cast(unsigned short, h);
}

// swizzled LDS byte offset: 128B rows, XOR bits 4-6 with row&7
__device__ __forceinline__ int lds_off(int row, int byte_in_row) {
    return row * 128 + (byte_in_row ^ ((row & 7) << 4));
}

// ---------------------------------------------------------------------------
__global__ __launch_bounds__(256) void gate_kernel(
    const float* __restrict__ x, const float* __restrict__ Wg,
    const float* __restrict__ bg, float* __restrict__ out,
    int* __restrict__ gates)
{
    int b = blockIdx.x;
    int tid = threadIdx.x;

    float acc[EE];
#pragma unroll
    for (int e = 0; e < EE; ++e) acc[e] = 0.f;

    for (int d = tid; d < DD; d += 256) {
        float xs = 0.f;
        const float* xp = x + (size_t)b * SS * DD + d;
#pragma unroll
        for (int s = 0; s < SS; ++s) xs += xp[(size_t)s * DD];
#pragma unroll
        for (int e = 0; e < EE; ++e) acc[e] += xs * Wg[d * EE + e];
    }

    __shared__ float red[EE][256];
#pragma unroll
    for (int e = 0; e < EE; ++e) red[e][tid] = acc[e];
    __syncthreads();
    for (int off = 128; off > 0; off >>= 1) {
        if (tid < off) {
#pragma unroll
            for (int e = 0; e < EE; ++e) red[e][tid] += red[e][tid + off];
        }
        __syncthreads();
    }

    if (tid == 0) {
        float lg[EE], p[EE];
        float m = -1e30f;
#pragma unroll
        for (int e = 0; e < EE; ++e) {
            lg[e] = red[e][0] / (float)SS + bg[e];
            m = fmaxf(m, lg[e]);
        }
        float sum = 0.f;
#pragma unroll
        for (int e = 0; e < EE; ++e) { p[e] = expf(lg[e] - m); sum += p[e]; }
        float inv = 1.f / sum;
#pragma unroll
        for (int e = 0; e < EE; ++e) p[e] *= inv;

        int i1 = 0;
        for (int e = 1; e < EE; ++e) if (p[e] > p[i1]) i1 = e;
        int i2 = (i1 == 0) ? 1 : 0;
        for (int e = 0; e < EE; ++e) if (e != i1 && p[e] > p[i2]) i2 = e;

        float* prob_out = out + (size_t)BB * SS * DD;
        float* gate_out = prob_out + BB * KK;
        prob_out[b * KK + 0] = p[i1];
        prob_out[b * KK + 1] = p[i2];
        gate_out[b * KK + 0] = (float)i1;
        gate_out[b * KK + 1] = (float)i2;
        gates[b * KK + 0] = i1;
        gates[b * KK + 1] = i2;
    }
}

// ---------------------------------------------------------------------------
// schedule: group pairs by expert, tiles of 4 pairs (BM=128 rows)
__global__ void sched_kernel(int* __restrict__ wsi)
{
    if (threadIdx.x != 0 || blockIdx.x != 0) return;
    const int* gates = wsi;
    int* spair = wsi + 64;
    int* te_e = wsi + 128;
    int* te_s = wsi + 152;
    int* te_n = wsi + 176;

    int cnt[EE];
    for (int e = 0; e < EE; ++e) cnt[e] = 0;
    for (int p = 0; p < NPAIR; ++p) cnt[gates[p]]++;
    int start[EE + 1];
    start[0] = 0;
    for (int e = 0; e < EE; ++e) start[e + 1] = start[e] + cnt[e];
    int fill[EE];
    for (int e = 0; e < EE; ++e) fill[e] = start[e];
    for (int p = 0; p < NPAIR; ++p) spair[fill[gates[p]]++] = p;

    int t = 0;
    for (int e = 0; e < EE; ++e) {
        for (int o = 0; o < cnt[e]; o += 4) {
            te_e[t] = e;
            te_s[t] = start[e] + o;
            te_n[t] = (cnt[e] - o) < 4 ? (cnt[e] - o) : 4;
            ++t;
        }
    }
    for (; t < MAXT; ++t) te_n[t] = 0;
}

// ---------------------------------------------------------------------------
__global__ __launch_bounds__(256) void init_kernel(
    const int* __restrict__ gates, const float* __restrict__ b2,
    float* __restrict__ out)
{
    int idx = blockIdx.x * 256 + threadIdx.x;
    if (idx >= BB * SS * DD) return;
    int b = idx / (SS * DD);
    int d = idx % DD;
    int e0 = gates[b * KK + 0];
    int e1 = gates[b * KK + 1];
    out[idx] = b2[e0 * DD + d] + b2[e1 * DD + d];
}

// ---------------------------------------------------------------------------
// Up GEMM: H = gelu(x @ W1[e] + b1[e]); BM=128 BN=64 BK=64, 4 waves 2x2
// (wave-tile 64x32). A: single reg set (x is L2/L3-resident). B: dual reg
// sets, issued ~2 phases ahead (cold HBM stream). LDS dbuf 48KB -> 3 blk/CU.
// grid (48, MAXT): stride 48 %8==0 -> same-expert tiles share an XCD L2.
__global__ __launch_bounds__(256, 3) void up_gemm(
    const float* __restrict__ x, const float* __restrict__ W1,
    const float* __restrict__ b1, const int* __restrict__ wsi,
    unsigned short* __restrict__ H)
{
    int tile = blockIdx.y;
    int np = wsi[176 + tile];
    if (np == 0) return;
    int e = wsi[128 + tile];
    int slot0 = wsi[152 + tile];
    int nt = blockIdx.x;
    int tid = threadIdx.x;
    int wid = tid >> 6, lane = tid & 63;
    int wm = wid >> 1, wn = wid & 1;

    __shared__ char lds[49152];   // per buf: A 16KB + B 8KB

    // A staging setup (x fp32 gathered rows -> bf16); clamp tail rows
    const float* asrc[4];
    int aoff[4];
#pragma unroll
    for (int i = 0; i < 4; ++i) {
        int c = tid + i * 256;            // 0..1023
        int row = c >> 3, ch = c & 7;     // 128 rows x 8 chunks of 8 elems
        int lp = row >> 5;
        int lpc = lp < np ? lp : np - 1;
        int pair = wsi[64 + slot0 + lpc];
        int b = pair >> 1;
        asrc[i] = x + ((size_t)(b * SS + (row & 31))) * DD + ch * 8;
        aoff[i] = lds_off(row, ch * 16);
    }
    // B staging setup: [n][k] LDS; lanes sweep n (coalesced), k strided
    int n = tid & 63, kq = tid >> 6;
    const float* bsrc = W1 + ((size_t)e * DD + kq * 16) * FFD + nt * 64 + n;
    int boff[2];
#pragma unroll
    for (int j4 = 0; j4 < 2; ++j4) boff[j4] = lds_off(n, kq * 32 + j4 * 16);

    f32x4 acc[4][2];
#pragma unroll
    for (int i = 0; i < 4; ++i)
#pragma unroll
        for (int j = 0; j < 2; ++j) acc[i][j] = (f32x4)0.f;

    float bB0[16], bB1[16];
    float4 a4[4][2];

    auto issueA = [&](int k0) {
#pragma unroll
        for (int i = 0; i < 4; ++i) {
            a4[i][0] = *(const float4*)(asrc[i] + k0);
            a4[i][1] = *(const float4*)(asrc[i] + k0 + 4);
        }
    };
    auto issueB = [&](float* bB, int k0) {
        const float* wp = bsrc + (size_t)k0 * FFD;
#pragma unroll
        for (int j = 0; j < 16; ++j) bB[j] = wp[(size_t)j * FFD];
    };
    auto storeA = [&](int p) {
        char* Al = lds + p * 24576;
#pragma unroll
        for (int i = 0; i < 4; ++i) {
            us8 u;
            u[0] = f2bf(a4[i][0].x); u[1] = f2bf(a4[i][0].y);
            u[2] = f2bf(a4[i][0].z); u[3] = f2bf(a4[i][0].w);
            u[4] = f2bf(a4[i][1].x); u[5] = f2bf(a4[i][1].y);
            u[6] = f2bf(a4[i][1].z); u[7] = f2bf(a4[i][1].w);
            *(us8*)(Al + aoff[i]) = u;
        }
    };
    auto storeB = [&](int p, const float* bB) {
        char* Bl = lds + p * 24576 + 16384;
#pragma unroll
        for (int j4 = 0; j4 < 2; ++j4) {
            us8 u;
#pragma unroll
            for (int m = 0; m < 8; ++m) u[m] = f2bf(bB[j4 * 8 + m]);
            *(us8*)(Bl + boff[j4]) = u;
        }
    };
    auto compute = [&](int p) {
        char* Al = lds + p * 24576;
        char* Bl = Al + 16384;
#pragma unroll
        for (int kk = 0; kk < 2; ++kk) {
            int kb = kk * 64 + (lane >> 4) * 16;
            short8 af[4], bf[2];
#pragma unroll
            for (int mf = 0; mf < 4; ++mf)
                af[mf] = *(short8*)(Al + lds_off(wm * 64 + mf * 16 + (lane & 15), kb));
#pragma unroll
            for (int nf = 0; nf < 2; ++nf)
                bf[nf] = *(short8*)(Bl + lds_off(wn * 32 + nf * 16 + (lane & 15), kb));
#pragma unroll
            for (int mf = 0; mf < 4; ++mf)
#pragma unroll
                for (int nf = 0; nf < 2; ++nf)
                    acc[mf][nf] = __builtin_amdgcn_mfma_f32_16x16x32_bf16(
                        af[mf], bf[nf], acc[mf][nf], 0, 0, 0);
        }
    };

    // prologue: buf0 = k0; a4 <- k1; b1 <- k1
    issueA(0);
    issueB(bB0, 0);
    storeA(0);
    storeB(0, bB0);
    issueA(64);
    issueB(bB1, 64);
    __syncthreads();

    // 12 k-steps, unrolled by 2 (buf parity static)
    for (int s = 0; s < 12; s += 2) {
        // even iter s: compute buf0; fill buf1 with k=s+1
        if (s + 2 < 12) issueB(bB0, (s + 2) * 64);
        compute(0);
        storeA(1);
        storeB(1, bB1);
        if (s + 2 < 12) issueA((s + 2) * 64);
        __syncthreads();
        // odd iter s+1: compute buf1; fill buf0 with k=s+2
        if (s + 3 < 12) issueB(bB1, (s + 3) * 64);
        compute(1);
        if (s + 2 < 12) {
            storeA(0);
            storeB(0, bB0);
            issueA((s + 3) * 64);
        }
        __syncthreads();
    }

    // epilogue: bias + exact gelu -> bf16 H (grouped slot rows)
    float bias[2];
#pragma unroll
    for (int nf = 0; nf < 2; ++nf)
        bias[nf] = b1[e * FFD + nt * 64 + wn * 32 + nf * 16 + (lane & 15)];
#pragma unroll
    for (int mf = 0; mf < 4; ++mf) {
#pragma unroll
        for (int i = 0; i < 4; ++i) {
            int row = wm * 64 + mf * 16 + (lane >> 4) * 4 + i;
            if ((row >> 5) >= np) continue;
            size_t srow = (size_t)(slot0 * 32 + row);
#pragma unroll
            for (int nf = 0; nf < 2; ++nf) {
                int f = nt * 64 + wn * 32 + nf * 16 + (lane & 15);
                float h = acc[mf][nf][i] + bias[nf];
                float g = 0.5f * h * (1.0f + erff(h * 0.70710678118654752f));
                H[srow * FFD + f] = f2bf(g);
            }
        }
    }
}

// ---------------------------------------------------------------------------
// Down GEMM: out += H @ W2[e]; BM=128 BN=64 BK=64, K split x4.
// A tile via global_load_lds (H already bf16): linear LDS dest, swizzle
// applied to the GLOBAL source chunk index (ch = c ^ (row&7)) so the
// swizzled ds_read in compute() sees the right data (rule #21).
// grid (16 nt [12 real; stride%8==0 for XCD-L2 W2 reuse], MAXT, 4)
__global__ __launch_bounds__(256, 3) void down_gemm(
    const unsigned short* __restrict__ H, const float* __restrict__ W2,
    const int* __restrict__ wsi, float* __restrict__ out)
{
    int nt = blockIdx.x;
    if (nt >= DD / 64) return;
    int tile = blockIdx.y;
    int np = wsi[176 + tile];
    if (np == 0) return;
    int e = wsi[128 + tile];
    int slot0 = wsi[152 + tile];
    int zb = blockIdx.z * (FFD / 4);
    int tid = threadIdx.x;
    int wid = tid >> 6, lane = tid & 63;
    int wm = wid >> 1, wn = wid & 1;

    __shared__ char lds[49152];

    // A via global_load_lds: per-lane global src (source-swizzled chunk),
    // wave-uniform LDS dest base + lane*16.
    const unsigned short* agsrc[4];
    int aldst[4];
#pragma unroll
    for (int i = 0; i < 4; ++i) {
        int q = i * 256 + tid;
        int row = q >> 3, c = q & 7;
        int rc = row < np * 32 ? row : np * 32 - 1;
        int ch = c ^ (row & 7);      // inverse swizzle on source
        agsrc[i] = H + (size_t)(slot0 * 32 + rc) * FFD + zb + ch * 8;
        aldst[i] = (i * 256 + (tid & 192)) * 16;   // wave-uniform
    }
    int n = tid & 63, kq = tid >> 6;
    const float* bsrc = W2 + ((size_t)e * FFD + zb + kq * 16) * DD + nt * 64 + n;
    int boff[2];
#pragma unroll
    for (int j4 = 0; j4 < 2; ++j4) boff[j4] = lds_off(n, kq * 32 + j4 * 16);

    f32x4 acc[4][2];
#pragma unroll
    for (int i = 0; i < 4; ++i)
#pragma unroll
        for (int j = 0; j < 2; ++j) acc[i][j] = (f32x4)0.f;

    float bB0[16], bB1[16];

    auto gloadA = [&](int p, int k0) {
        char* Al = lds + p * 24576;
#pragma unroll
        for (int i = 0; i < 4; ++i)
            __builtin_amdgcn_global_load_lds(
                (const GLOBAL_AS void*)(agsrc[i] + k0),
                (LDS_AS void*)(Al + aldst[i]), 16, 0, 0);
    };
    auto issueB = [&](float* bB, int k0) {
        const float* wp = bsrc + (size_t)k0 * DD;
#pragma unroll
        for (int j = 0; j < 16; ++j) bB[j] = wp[(size_t)j * DD];
    };
    auto storeB = [&](int p, const float* bB) {
        char* Bl = lds + p * 24576 + 16384;
#pragma unroll
        for (int j4 = 0; j4 < 2; ++j4) {
            us8 u;
#pragma unroll
            for (int m = 0; m < 8; ++m) u[m] = f2bf(bB[j4 * 8 + m]);
            *(us8*)(Bl + boff[j4]) = u;
        }
    };
    auto compute = [&](int p) {
        char* Al = lds + p * 24576;
        char* Bl = Al + 16384;
#pragma unroll
        for (int kk = 0; kk < 2; ++kk) {
            int kb = kk * 64 + (lane >> 4) * 16;
            short8 af[4], bf[2];
#pragma unroll
            for (int mf = 0; mf < 4; ++mf)
                af[mf] = *(short8*)(Al + lds_off(wm * 64 + mf * 16 + (lane & 15), kb));
#pragma unroll
            for (int nf = 0; nf < 2; ++nf)
                bf[nf] = *(short8*)(Bl + lds_off(wn * 32 + nf * 16 + (lane & 15), kb));
#pragma unroll
            for (int mf = 0; mf < 4; ++mf)
#pragma unroll
                for (int nf = 0; nf < 2; ++nf)
                    acc[mf][nf] = __builtin_amdgcn_mfma_f32_16x16x32_bf16(
                        af[mf], bf[nf], acc[mf][nf], 0, 0, 0);
        }
    };

    // prologue: buf0 <- k0 (A async + B); b1 <- k1
    gloadA(0, 0);
    issueB(bB0, 0);
    storeB(0, bB0);
    issueB(bB1, 64);
    __syncthreads();   // drains gloadA(0) too

    for (int s = 0; s < 12; s += 2) {
        // even iter s: compute buf0; buf1 <- k=s+1
        gloadA(1, (s + 1) * 64);
        if (s + 2 < 12) issueB(bB0, (s + 2) * 64);
        compute(0);
        storeB(1, bB1);
        __syncthreads();
        // odd iter s+1: compute buf1; buf0 <- k=s+2
        if (s + 2 < 12) {
            gloadA(0, (s + 2) * 64);
            if (s + 3 < 12) issueB(bB1, (s + 3) * 64);
        }
        compute(1);
        if (s + 2 < 12) storeB(0, bB0);
        __syncthreads();
    }

    // epilogue: scatter atomic-add (bias pre-added by init_kernel)
#pragma unroll
    for (int mf = 0; mf < 4; ++mf) {
#pragma unroll
        for (int i = 0; i < 4; ++i) {
            int row = wm * 64 + mf * 16 + (lane >> 4) * 4 + i;
            int lp = row >> 5;
            if (lp >= np) continue;
            int pair = wsi[64 + slot0 + lp];
            int b = pair >> 1;
            int sI = row & 31;
            float* op = out + ((size_t)(b * SS + sI)) * DD + nt * 64 + wn * 32 + (lane & 15);
#pragma unroll
            for (int nf = 0; nf < 2; ++nf)
                atomicAdd(op + nf * 16, acc[mf][nf][i]);
        }
    }
}

// ---------------------------------------------------------------------------
extern "C" void kernel_launch(void* const* d_in, const int* in_sizes, int n_in,
                              void* d_out, int out_size, void* d_ws, size_t ws_size,
                              hipStream_t stream) {
    const float* x  = (const float*)d_in[0];
    const float* Wg = (const float*)d_in[2];
    const float* bg = (const float*)d_in[3];
    const float* W1 = (const float*)d_in[4];
    const float* b1 = (const float*)d_in[5];
    const float* W2 = (const float*)d_in[6];
    const float* b2 = (const float*)d_in[7];
    float* out = (float*)d_out;

    int* wsi = (int*)d_ws;
    unsigned short* H = (unsigned short*)((char*)d_ws + 1024);
    // ws needed: 1024 + 64*32*3072*2 = ~12.6 MB

    gate_kernel<<<BB, 256, 0, stream>>>(x, Wg, bg, out, wsi);
    sched_kernel<<<1, 64, 0, stream>>>(wsi);
    init_kernel<<<(BB * SS * DD + 255) / 256, 256, 0, stream>>>(wsi, b2, out);
    up_gemm<<<dim3(48, MAXT), 256, 0, stream>>>(x, W1, b1, wsi, H);
    down_gemm<<<dim3(16, MAXT, 4), 256, 0, stream>>>(H, W2, wsi, out);
}

// Round 7
// 110.642 us; speedup vs baseline: 11.5773x; 1.0761x over previous
//
#include <hip/hip_runtime.h>
#include <hip/hip_bf16.h>
#include <math.h>

#define BB 32
#define SS 32
#define DD 768
#define FFD 3072
#define EE 8
#define KK 2
#define NPAIR 64
#define MAXT 22   // max expert-aligned tiles of 4 pairs: sum ceil(cnt/4) <= (64+24)/4

#define GLOBAL_AS __attribute__((address_space(1)))
#define LDS_AS    __attribute__((address_space(3)))

typedef __attribute__((ext_vector_type(8))) short short8;
typedef __attribute__((ext_vector_type(4))) float f32x4;
typedef __attribute__((ext_vector_type(8))) unsigned short us8;

// ws int layout (ints): [0..63] gates, [64..127] spair (grouped by expert),
//   [128..149] te_expert, [152..173] te_slot0, [176..197] te_np,
//   [200..263] slot_of_pair (inverse of spair)  -> int region ends @ byte 1056
// H    (bf16 [2048][3072])   @ ws byte 4096                  (12.58 MB)
// part (f32 [2][2048][768])  @ ws byte 4096+12582912         (12.58 MB)
// ROUND-6 BUG: H_OFF was 1024, overlapping slotof[56..63] -> garbage slot
// index in reduce -> OOB read -> device abort. H_OFF now 4096.

#define H_OFF    4096
#define PART_OFF (H_OFF + 12582912)
#define PART_Z   (2048 * 768)
#define WS_NEED  ((size_t)PART_OFF + 2ull * PART_Z * 4ull)

__device__ __forceinline__ unsigned short f2bf(float f) {
    __hip_bfloat16 h = __float2bfloat16(f);
    return __builtin_bit_cast(unsigned short, h);
}

// swizzled LDS byte offset: 128B rows, XOR bits 4-6 with row&7
__device__ __forceinline__ int lds_off(int row, int byte_in_row) {
    return row * 128 + (byte_in_row ^ ((row & 7) << 4));
}

// ---------------------------------------------------------------------------
__global__ __launch_bounds__(256) void gate_kernel(
    const float* __restrict__ x, const float* __restrict__ Wg,
    const float* __restrict__ bg, float* __restrict__ out,
    int* __restrict__ gates)
{
    int b = blockIdx.x;
    int tid = threadIdx.x;

    float acc[EE];
#pragma unroll
    for (int e = 0; e < EE; ++e) acc[e] = 0.f;

    for (int d = tid; d < DD; d += 256) {
        float xs = 0.f;
        const float* xp = x + (size_t)b * SS * DD + d;
#pragma unroll
        for (int s = 0; s < SS; ++s) xs += xp[(size_t)s * DD];
#pragma unroll
        for (int e = 0; e < EE; ++e) acc[e] += xs * Wg[d * EE + e];
    }

    __shared__ float red[EE][256];
#pragma unroll
    for (int e = 0; e < EE; ++e) red[e][tid] = acc[e];
    __syncthreads();
    for (int off = 128; off > 0; off >>= 1) {
        if (tid < off) {
#pragma unroll
            for (int e = 0; e < EE; ++e) red[e][tid] += red[e][tid + off];
        }
        __syncthreads();
    }

    if (tid == 0) {
        float lg[EE], p[EE];
        float m = -1e30f;
#pragma unroll
        for (int e = 0; e < EE; ++e) {
            lg[e] = red[e][0] / (float)SS + bg[e];
            m = fmaxf(m, lg[e]);
        }
        float sum = 0.f;
#pragma unroll
        for (int e = 0; e < EE; ++e) { p[e] = expf(lg[e] - m); sum += p[e]; }
        float inv = 1.f / sum;
#pragma unroll
        for (int e = 0; e < EE; ++e) p[e] *= inv;

        int i1 = 0;
        for (int e = 1; e < EE; ++e) if (p[e] > p[i1]) i1 = e;
        int i2 = (i1 == 0) ? 1 : 0;
        for (int e = 0; e < EE; ++e) if (e != i1 && p[e] > p[i2]) i2 = e;

        float* prob_out = out + (size_t)BB * SS * DD;
        float* gate_out = prob_out + BB * KK;
        prob_out[b * KK + 0] = p[i1];
        prob_out[b * KK + 1] = p[i2];
        gate_out[b * KK + 0] = (float)i1;
        gate_out[b * KK + 1] = (float)i2;
        gates[b * KK + 0] = i1;
        gates[b * KK + 1] = i2;
    }
}

// ---------------------------------------------------------------------------
// schedule: group pairs by expert, tiles of 4 pairs (BM=128 rows)
__global__ void sched_kernel(int* __restrict__ wsi)
{
    if (threadIdx.x != 0 || blockIdx.x != 0) return;
    const int* gates = wsi;
    int* spair = wsi + 64;
    int* te_e = wsi + 128;
    int* te_s = wsi + 152;
    int* te_n = wsi + 176;
    int* slotof = wsi + 200;

    int cnt[EE];
    for (int e = 0; e < EE; ++e) cnt[e] = 0;
    for (int p = 0; p < NPAIR; ++p) cnt[gates[p]]++;
    int start[EE + 1];
    start[0] = 0;
    for (int e = 0; e < EE; ++e) start[e + 1] = start[e] + cnt[e];
    int fill[EE];
    for (int e = 0; e < EE; ++e) fill[e] = start[e];
    for (int p = 0; p < NPAIR; ++p) {
        int s = fill[gates[p]]++;
        spair[s] = p;
        slotof[p] = s;
    }

    int t = 0;
    for (int e = 0; e < EE; ++e) {
        for (int o = 0; o < cnt[e]; o += 4) {
            te_e[t] = e;
            te_s[t] = start[e] + o;
            te_n[t] = (cnt[e] - o) < 4 ? (cnt[e] - o) : 4;
            ++t;
        }
    }
    for (; t < MAXT; ++t) te_n[t] = 0;
}

// ---------------------------------------------------------------------------
// Fallback-path init: out = bias sums (down<ATOMIC> adds on top)
__global__ __launch_bounds__(256) void init_kernel(
    const int* __restrict__ gates, const float* __restrict__ b2,
    float* __restrict__ out)
{
    int idx = blockIdx.x * 256 + threadIdx.x;
    if (idx >= BB * SS * DD) return;
    int b = idx / (SS * DD);
    int d = idx % DD;
    int e0 = gates[b * KK + 0];
    int e1 = gates[b * KK + 1];
    out[idx] = b2[e0 * DD + d] + b2[e1 * DD + d];
}

// ---------------------------------------------------------------------------
// Up GEMM: H = gelu(x @ W1[e] + b1[e]); BM=128 BN=128 BK=64, 8 waves (2Mx4N,
// wave-tile 64x32). A single reg set (x L3-resident), B dual reg sets (cold
// HBM stream, ~1.5 phases lead). LDS dbuf 64KB -> 2 blk/CU = 16 waves/CU.
// grid (24 nt, MAXT): stride 24 %8==0 -> same-expert tiles share an XCD L2.
__global__ __launch_bounds__(512, 4) void up_gemm(
    const float* __restrict__ x, const float* __restrict__ W1,
    const float* __restrict__ b1, const int* __restrict__ wsi,
    unsigned short* __restrict__ H)
{
    int tile = blockIdx.y;
    int np = wsi[176 + tile];
    if (np == 0) return;
    int e = wsi[128 + tile];
    int slot0 = wsi[152 + tile];
    int nt = blockIdx.x;
    int tid = threadIdx.x;
    int wid = tid >> 6, lane = tid & 63;
    int wm = wid >> 2, wn = wid & 3;     // 2 x 4 wave grid

    __shared__ char lds[65536];   // per buf: A 16KB + B 16KB

    // A staging setup: 128 rows x 8 chunks(8 fp32) = 1024 chunks, 2/thread
    const float* asrc[2];
    int aoff[2];
#pragma unroll
    for (int i = 0; i < 2; ++i) {
        int c = i * 512 + tid;
        int row = c >> 3, ch = c & 7;
        int lp = row >> 5;
        int lpc = lp < np ? lp : np - 1;
        int pair = wsi[64 + slot0 + lpc];
        int b = pair >> 1;
        asrc[i] = x + ((size_t)(b * SS + (row & 31))) * DD + ch * 8;
        aoff[i] = lds_off(row, ch * 16);
    }
    // B staging: [n][k] LDS; 128 n x 64 k; lanes sweep n, k strided; 16/thread
    int n = tid & 127, kq = tid >> 7;    // kq in [0,4), rows kq*16+j
    const float* bsrc = W1 + ((size_t)e * DD + kq * 16) * FFD + nt * 128 + n;
    int boff[2];
#pragma unroll
    for (int j4 = 0; j4 < 2; ++j4) boff[j4] = lds_off(n, kq * 32 + j4 * 16);

    f32x4 acc[4][2];
#pragma unroll
    for (int i = 0; i < 4; ++i)
#pragma unroll
        for (int j = 0; j < 2; ++j) acc[i][j] = (f32x4)0.f;

    float bB0[16], bB1[16];
    float4 a4[2][2];

    auto issueA = [&](int k0) {
#pragma unroll
        for (int i = 0; i < 2; ++i) {
            a4[i][0] = *(const float4*)(asrc[i] + k0);
            a4[i][1] = *(const float4*)(asrc[i] + k0 + 4);
        }
    };
    auto issueB = [&](float* bB, int k0) {
        const float* wp = bsrc + (size_t)k0 * FFD;
#pragma unroll
        for (int j = 0; j < 16; ++j) bB[j] = wp[(size_t)j * FFD];
    };
    auto storeA = [&](int p) {
        char* Al = lds + p * 32768;
#pragma unroll
        for (int i = 0; i < 2; ++i) {
            us8 u;
            u[0] = f2bf(a4[i][0].x); u[1] = f2bf(a4[i][0].y);
            u[2] = f2bf(a4[i][0].z); u[3] = f2bf(a4[i][0].w);
            u[4] = f2bf(a4[i][1].x); u[5] = f2bf(a4[i][1].y);
            u[6] = f2bf(a4[i][1].z); u[7] = f2bf(a4[i][1].w);
            *(us8*)(Al + aoff[i]) = u;
        }
    };
    auto storeB = [&](int p, const float* bB) {
        char* Bl = lds + p * 32768 + 16384;
#pragma unroll
        for (int j4 = 0; j4 < 2; ++j4) {
            us8 u;
#pragma unroll
            for (int m = 0; m < 8; ++m) u[m] = f2bf(bB[j4 * 8 + m]);
            *(us8*)(Bl + boff[j4]) = u;
        }
    };
    auto compute = [&](int p) {
        char* Al = lds + p * 32768;
        char* Bl = Al + 16384;
#pragma unroll
        for (int kk = 0; kk < 2; ++kk) {
            int kb = kk * 64 + (lane >> 4) * 16;
            short8 af[4], bf[2];
#pragma unroll
            for (int mf = 0; mf < 4; ++mf)
                af[mf] = *(short8*)(Al + lds_off(wm * 64 + mf * 16 + (lane & 15), kb));
#pragma unroll
            for (int nf = 0; nf < 2; ++nf)
                bf[nf] = *(short8*)(Bl + lds_off(wn * 32 + nf * 16 + (lane & 15), kb));
#pragma unroll
            for (int mf = 0; mf < 4; ++mf)
#pragma unroll
                for (int nf = 0; nf < 2; ++nf)
                    acc[mf][nf] = __builtin_amdgcn_mfma_f32_16x16x32_bf16(
                        af[mf], bf[nf], acc[mf][nf], 0, 0, 0);
        }
    };

    // prologue
    issueA(0);
    issueB(bB0, 0);
    storeA(0);
    storeB(0, bB0);
    issueA(64);
    issueB(bB1, 64);
    __syncthreads();

    // 12 k-steps, unrolled by 2 (buffer parity static)
    for (int s = 0; s < 12; s += 2) {
        if (s + 2 < 12) issueB(bB0, (s + 2) * 64);
        compute(0);
        storeA(1);
        storeB(1, bB1);
        if (s + 2 < 12) issueA((s + 2) * 64);
        __syncthreads();
        if (s + 3 < 12) issueB(bB1, (s + 3) * 64);
        compute(1);
        if (s + 2 < 12) {
            storeA(0);
            storeB(0, bB0);
            issueA((s + 3) * 64);
        }
        __syncthreads();
    }

    // epilogue: bias + exact gelu -> bf16 H (grouped slot rows)
    float bias[2];
#pragma unroll
    for (int nf = 0; nf < 2; ++nf)
        bias[nf] = b1[e * FFD + nt * 128 + wn * 32 + nf * 16 + (lane & 15)];
#pragma unroll
    for (int mf = 0; mf < 4; ++mf) {
#pragma unroll
        for (int i = 0; i < 4; ++i) {
            int row = wm * 64 + mf * 16 + (lane >> 4) * 4 + i;
            if ((row >> 5) >= np) continue;
            size_t srow = (size_t)(slot0 * 32 + row);
#pragma unroll
            for (int nf = 0; nf < 2; ++nf) {
                int f = nt * 128 + wn * 32 + nf * 16 + (lane & 15);
                float h = acc[mf][nf][i] + bias[nf];
                float g = 0.5f * h * (1.0f + erff(h * 0.70710678118654752f));
                H[srow * FFD + f] = f2bf(g);
            }
        }
    }
}

// ---------------------------------------------------------------------------
// Down GEMM: BM=128 BN=64 BK=64, z=2 K-split, 8 waves (4Mx2N, wave-tile
// 32x32). A via global_load_lds (src-swizzled), B dual reg sets. LDS dbuf
// 48KB. MODE 0: plain stores to part[z] (reduce combines). MODE 1: atomic
// into out (fallback when ws too small; init pre-adds bias).
// grid (MAXT tile-fastest [same-expert tiles adjacent->same XCD], 12 nt, 2 z)
template<int MODE>
__global__ __launch_bounds__(512, 6) void down_gemm(
    const unsigned short* __restrict__ H, const float* __restrict__ W2,
    const int* __restrict__ wsi, float* __restrict__ part,
    float* __restrict__ out)
{
    int tile = blockIdx.x;
    int np = wsi[176 + tile];
    if (np == 0) return;
    int e = wsi[128 + tile];
    int slot0 = wsi[152 + tile];
    int nt = blockIdx.y;
    int z = blockIdx.z;
    int zb = z * (FFD / 2);
    int tid = threadIdx.x;
    int wid = tid >> 6, lane = tid & 63;
    int wm = wid >> 1, wn = wid & 1;     // 4 x 2 wave grid

    __shared__ char lds[49152];   // per buf: A 16KB + B 8KB

    // A via global_load_lds: 1024 16B-chunks, 2/thread; linear LDS dest,
    // swizzle applied to GLOBAL source chunk (rule #21)
    const unsigned short* agsrc[2];
    int aldst[2];
#pragma unroll
    for (int i = 0; i < 2; ++i) {
        int q = i * 512 + tid;
        int row = q >> 3, c = q & 7;
        int rc = row < np * 32 ? row : np * 32 - 1;
        int ch = c ^ (row & 7);
        agsrc[i] = H + (size_t)(slot0 * 32 + rc) * FFD + zb + ch * 8;
        aldst[i] = (i * 512 + (tid & 448)) * 16;   // wave-uniform base
    }
    // B staging: 64 n x 64 k; kq in [0,8), rows kq*8+j; 8 loads/thread
    int n = tid & 63, kq = tid >> 6;
    const float* bsrc = W2 + ((size_t)e * FFD + zb + kq * 8) * DD + nt * 64 + n;
    int boff = lds_off(n, kq * 16);

    f32x4 acc[2][2];
#pragma unroll
    for (int i = 0; i < 2; ++i)
#pragma unroll
        for (int j = 0; j < 2; ++j) acc[i][j] = (f32x4)0.f;

    float bB0[8], bB1[8];

    auto gloadA = [&](int p, int k0) {
        char* Al = lds + p * 24576;
#pragma unroll
        for (int i = 0; i < 2; ++i)
            __builtin_amdgcn_global_load_lds(
                (const GLOBAL_AS void*)(agsrc[i] + k0),
                (LDS_AS void*)(Al + aldst[i]), 16, 0, 0);
    };
    auto issueB = [&](float* bB, int k0) {
        const float* wp = bsrc + (size_t)k0 * DD;
#pragma unroll
        for (int j = 0; j < 8; ++j) bB[j] = wp[(size_t)j * DD];
    };
    auto storeB = [&](int p, const float* bB) {
        char* Bl = lds + p * 24576 + 16384;
        us8 u;
#pragma unroll
        for (int m = 0; m < 8; ++m) u[m] = f2bf(bB[m]);
        *(us8*)(Bl + boff) = u;
    };
    auto compute = [&](int p) {
        char* Al = lds + p * 24576;
        char* Bl = Al + 16384;
#pragma unroll
        for (int kk = 0; kk < 2; ++kk) {
            int kb = kk * 64 + (lane >> 4) * 16;
            short8 af[2], bf[2];
#pragma unroll
            for (int mf = 0; mf < 2; ++mf)
                af[mf] = *(short8*)(Al + lds_off(wm * 32 + mf * 16 + (lane & 15), kb));
#pragma unroll
            for (int nf = 0; nf < 2; ++nf)
                bf[nf] = *(short8*)(Bl + lds_off(wn * 32 + nf * 16 + (lane & 15), kb));
#pragma unroll
            for (int mf = 0; mf < 2; ++mf)
#pragma unroll
                for (int nf = 0; nf < 2; ++nf)
                    acc[mf][nf] = __builtin_amdgcn_mfma_f32_16x16x32_bf16(
                        af[mf], bf[nf], acc[mf][nf], 0, 0, 0);
        }
    };

    // prologue
    gloadA(0, 0);
    issueB(bB0, 0);
    storeB(0, bB0);
    issueB(bB1, 64);
    __syncthreads();

    // 24 k-steps (1536/64), unrolled by 2
    for (int s = 0; s < 24; s += 2) {
        gloadA(1, (s + 1) * 64);
        if (s + 2 < 24) issueB(bB0, (s + 2) * 64);
        compute(0);
        storeB(1, bB1);
        __syncthreads();
        if (s + 2 < 24) {
            gloadA(0, (s + 2) * 64);
            if (s + 3 < 24) issueB(bB1, (s + 3) * 64);
        }
        compute(1);
        if (s + 2 < 24) storeB(0, bB0);
        __syncthreads();
    }

    // epilogue
#pragma unroll
    for (int mf = 0; mf < 2; ++mf) {
#pragma unroll
        for (int i = 0; i < 4; ++i) {
            int row = wm * 32 + mf * 16 + (lane >> 4) * 4 + i;
            int lp = row >> 5;
            if (lp >= np) continue;
            int col = nt * 64 + wn * 32 + (lane & 15);
            if (MODE == 0) {
                size_t srow = (size_t)(slot0 * 32 + row);
                float* pp = part + (size_t)z * PART_Z + srow * DD + col;
#pragma unroll
                for (int nf = 0; nf < 2; ++nf) pp[nf * 16] = acc[mf][nf][i];
            } else {
                int pair = wsi[64 + slot0 + lp];
                int b = pair >> 1;
                int sI = row & 31;
                float* op = out + ((size_t)(b * SS + sI)) * DD + col;
#pragma unroll
                for (int nf = 0; nf < 2; ++nf)
                    atomicAdd(op + nf * 16, acc[mf][nf][i]);
            }
        }
    }
}

// ---------------------------------------------------------------------------
// Reduce (PART path): out[b,s,d] = sum_k sum_z part[z][slotof[b*2+k]*32+s][d]
//                                  + b2[e0,d] + b2[e1,d]
__global__ __launch_bounds__(512) void reduce_kernel(
    const float* __restrict__ part, const int* __restrict__ wsi,
    const float* __restrict__ b2, float* __restrict__ out)
{
    int idx = blockIdx.x * 512 + threadIdx.x;   // over B*S*D = 786432
    int b = idx / (SS * DD);
    int r = idx - b * (SS * DD);
    int s = r / DD;
    int d = r - s * DD;

    int e0 = wsi[b * KK + 0];
    int e1 = wsi[b * KK + 1];
    int sl0 = wsi[200 + b * KK + 0];
    int sl1 = wsi[200 + b * KK + 1];
    size_t r0 = (size_t)(sl0 * 32 + s) * DD + d;
    size_t r1 = (size_t)(sl1 * 32 + s) * DD + d;

    float v = part[r0] + part[PART_Z + r0]
            + part[r1] + part[PART_Z + r1]
            + b2[e0 * DD + d] + b2[e1 * DD + d];
    out[idx] = v;
}

// ---------------------------------------------------------------------------
extern "C" void kernel_launch(void* const* d_in, const int* in_sizes, int n_in,
                              void* d_out, int out_size, void* d_ws, size_t ws_size,
                              hipStream_t stream) {
    const float* x  = (const float*)d_in[0];
    const float* Wg = (const float*)d_in[2];
    const float* bg = (const float*)d_in[3];
    const float* W1 = (const float*)d_in[4];
    const float* b1 = (const float*)d_in[5];
    const float* W2 = (const float*)d_in[6];
    const float* b2 = (const float*)d_in[7];
    float* out = (float*)d_out;

    int* wsi = (int*)d_ws;
    unsigned short* H = (unsigned short*)((char*)d_ws + H_OFF);
    float* part = (float*)((char*)d_ws + PART_OFF);

    gate_kernel<<<BB, 256, 0, stream>>>(x, Wg, bg, out, wsi);
    sched_kernel<<<1, 64, 0, stream>>>(wsi);
    up_gemm<<<dim3(24, MAXT), 512, 0, stream>>>(x, W1, b1, wsi, H);

    if (ws_size >= WS_NEED) {
        down_gemm<0><<<dim3(MAXT, 12, 2), 512, 0, stream>>>(H, W2, wsi, part, out);
        reduce_kernel<<<(BB * SS * DD) / 512, 512, 0, stream>>>(part, wsi, b2, out);
    } else {
        init_kernel<<<(BB * SS * DD + 255) / 256, 256, 0, stream>>>(wsi, b2, out);
        down_gemm<1><<<dim3(MAXT, 12, 2), 512, 0, stream>>>(H, W2, wsi, part, out);
    }
}